// Round 8
// baseline (164.766 us; speedup 1.0000x reference)
//
#include <hip/hip_runtime.h>
#include <hip/hip_bf16.h>

typedef unsigned int u32;
typedef unsigned long long u64;

// ---------------- packed-weight layout in d_ws (u64 indices) ----------------
#define OC1 0      // conv1: 3 nz ch-pair words, then 3 sign ch-pair words
#define OC2 8      // conv2: per out-ch 6 u64: [0..2]=nz rows, [3..5]=sign rows
#define WCONV 104
// fc1: per j (pad 128), stride 16: word 2k=nz_k, 2k+1=sign_k (k=0..6), 14/15 pad
#define OF1 104    // 128*16 = 2048
// fc2: per j (pad 128), stride 6: [nz0,sg0,nz1,sg1,pad,pad]
#define OF2 2152   // 128*6 = 768
// fc3: per j (10), stride 4: [nz0,sg0,nz1,sg1]
#define OF3 2920   // 10*4 = 40
#define WTOT 2960

__global__ void pack_w(const float* __restrict__ w1, const float* __restrict__ w2,
                       const float* __restrict__ f1, const float* __restrict__ f2,
                       const float* __restrict__ f3, u64* __restrict__ P) {
    int g = blockIdx.x * 256 + threadIdx.x;
    if (g < 2048) {                      // fc1: j*16 + w, interleaved nz/sign
        int j = g >> 4, w = g & 15;
        u64 v = 0;
        if (w < 14 && j < 120) {
            int k = w >> 1; bool sp = (w & 1);
            for (int f = 0; f < 4; f++) {
                int p = 4 * k + f;
                if (p < 25)
                    for (int ch = 0; ch < 16; ch++) {
                        float x = f1[j * 400 + ch * 25 + p];
                        bool b = sp ? (x < 0.0f) : (x != 0.0f);
                        if (b) v |= 1ull << (f * 16 + ch);
                    }
            }
        }
        P[OF1 + g] = v;
    } else if (g < 2816) {               // fc2: j*6 + w, [nz0,sg0,nz1,sg1,pad,pad]
        int g2 = g - 2048, j = g2 / 6, w = g2 % 6;
        u64 v = 0;
        if (w < 4 && j < 84) {
            int h = w >> 1; bool sp = (w & 1);
            for (int b = 0; b < 64; b++) {
                int k = h * 64 + b;
                if (k < 120) {
                    float x = f2[j * 120 + k];
                    bool bb = sp ? (x < 0.0f) : (x != 0.0f);
                    if (bb) v |= 1ull << b;
                }
            }
        }
        P[OF2 + g2] = v;
    } else if (g < 2856) {               // fc3: j*4 + w, [nz0,sg0,nz1,sg1]
        int g3 = g - 2816, j = g3 >> 2, w = g3 & 3;
        int h = w >> 1; bool sp = (w & 1);
        u64 v = 0;
        for (int b = 0; b < 64; b++) {
            int k = h * 64 + b;
            if (k < 84) {
                float x = f3[j * 84 + k];
                bool bb = sp ? (x < 0.0f) : (x != 0.0f);
                if (bb) v |= 1ull << b;
            }
        }
        P[OF3 + g3] = v;
    } else if (g < 2952) {               // conv2
        int c = g - 2856, ch = c / 6, w = c % 6;
        bool sp = (w >= 3); int wp = w % 3;
        u64 v = 0;
        for (int half = 0; half < 2; half++) {
            int r = 2 * wp + half;
            if (r < 5) {
                u32 rowv = 0;
                for (int ci = 0; ci < 6; ci++)
                    for (int cc = 0; cc < 5; cc++) {
                        float x = w2[((ch * 6 + ci) * 5 + r) * 5 + cc];
                        bool b = sp ? (x < 0.0f) : (x != 0.0f);
                        int bit = (ci < 3) ? (5 * ci + cc) : (15 + 5 * (ci - 3) + cc);
                        if (b) rowv |= 1u << bit;
                    }
                v |= (u64)rowv << (32 * half);
            }
        }
        P[OC2 + ch * 6 + (sp ? 3 : 0) + wp] = v;
    } else if (g < 2958) {               // conv1
        int c = g - 2952;
        int pair = c % 3; bool sp = (c >= 3);
        u64 v = 0;
        for (int half = 0; half < 2; half++) {
            int ch = 2 * pair + half;
            u32 wd = 0;
            for (int r = 0; r < 5; r++)
                for (int cc = 0; cc < 5; cc++) {
                    float x = w1[ch * 25 + r * 5 + cc];
                    bool b = sp ? (x < 0.0f) : (x != 0.0f);
                    if (b) wd |= 1u << (6 * r + cc);
                }
            v |= (u64)wd << (32 * half);
        }
        P[OC1 + (sp ? 3 : 0) + pair] = v;
    }
}

#define G 8  // images per block (2 per wave, 4 waves)

__device__ __forceinline__ u32 sgnb(int v) { return (u32)v >> 31; }
__device__ __forceinline__ u32 nzb(int v)  { return (u32)(v | -v) >> 31; }
// Within one wave the DS pipe is FIFO; read-after-write through LDS needs only
// a compiler scheduling fence, not s_barrier:
#define WB() __builtin_amdgcn_wave_barrier()

__global__ __launch_bounds__(256, 8) void lenet_main(const float* __restrict__ X,
                                                     const u64* __restrict__ P,
                                                     float* __restrict__ out) {
    __shared__ u64 WL[WCONV];
    __shared__ u32 xs[G][32], xn[G][32];
    __shared__ u64 h1An[G][14], h1As[G][14], h1Bn[G][14], h1Bs[G][14];
    __shared__ u64 h2n[G][7], h2s[G][7];
    __shared__ u64 f1s[G][2], f1n[G][2], f2s[G][2], f2n[G][2];
    __shared__ float outb[G * 10];

    const int tid = threadIdx.x;
    const int wid = tid >> 6, lane = tid & 63;
    const int img0 = blockIdx.x * G;
    const int li0 = wid * 2;          // this wave owns local images li0, li0+1

    if (tid < WCONV) WL[tid] = P[tid];
    __syncthreads();                  // weight staging barrier

    // ---- input: float4 load + nibble binarize + shfl-xor pack; per-wave zero detect ----
    u64 zb = 0;
    {
        const float4* X4 = (const float4*)(X + (size_t)img0 * 1024);
        for (int it = 0; it < 8; it++) {
            int li = li0 + (it >> 2);
            int f4 = ((it & 3) << 6) + lane;      // float4 index within image
            float4 v = X4[li * 256 + f4];
            u32 s = (v.x < 0.0f ? 1u : 0u) | (v.y < 0.0f ? 2u : 0u)
                  | (v.z < 0.0f ? 4u : 0u) | (v.w < 0.0f ? 8u : 0u);
            u32 n = (v.x != 0.0f ? 1u : 0u) | (v.y != 0.0f ? 2u : 0u)
                  | (v.z != 0.0f ? 4u : 0u) | (v.w != 0.0f ? 8u : 0u);
            zb |= __ballot(n != 15u);
            int pos = 4 * (f4 & 7);
            u32 sw = s << pos, nw = n << pos;
            sw |= __shfl_xor((int)sw, 1); sw |= __shfl_xor((int)sw, 2); sw |= __shfl_xor((int)sw, 4);
            nw |= __shfl_xor((int)nw, 1); nw |= __shfl_xor((int)nw, 2); nw |= __shfl_xor((int)nw, 4);
            if ((lane & 7) == 0) { xs[li][f4 >> 3] = sw; xn[li][f4 >> 3] = nw; }
        }
    }
    // weight cleanliness (no exact-0 conv weights), from LDS, wave-uniform via ballot
    u64 db;
    {
        bool bad = false;
        if (lane < 51) {
            u64 w, exp;
            if (lane < 48) {
                int ch = lane / 3, k = lane % 3;
                w = WL[OC2 + ch * 6 + k];
                exp = (k < 2) ? 0x3FFFFFFF3FFFFFFFull : 0x000000003FFFFFFFull;
            } else {
                w = WL[OC1 + (lane - 48)];
                exp = 0x1F7DF7DF1F7DF7DFull;
            }
            bad = (w != exp);
        }
        db = __ballot(bad);
    }
    const bool fastp = ((zb | db) == 0);
    WB();

    // ---- conv1 + pool: 28 segments (2 img x 14 rows), 4 per pass, 7 passes ----
    {
        const int px = lane & 15;
        const int pxe = px < 14 ? px : 13;
        if (fastp) {
            u64 c1s[3];
            for (int p = 0; p < 3; p++) c1s[p] = WL[OC1 + 3 + p];
            for (int it = 0; it < 7; it++) {
                int seg = it * 4 + (lane >> 4);        // 0..27
                int im = seg >= 14 ? 1 : 0, py = seg - 14 * im, li = li0 + im;
                int oy = 2 * py;
                u32 rs[6];
                for (int k = 0; k < 6; k++) rs[k] = xs[li][oy + k];
                u32 cnt[6];
                for (int c = 0; c < 6; c++) cnt[c] = 255;
                for (int dx = 0; dx < 2; dx++) {
                    int t2 = 2 * pxe + dx;
                    u32 w0 = 0;
                    for (int r = 0; r < 5; r++) w0 |= ((rs[r] >> t2) & 31u) << (6 * r);
                    u32 w1 = (w0 >> 6) | (((rs[5] >> t2) & 31u) << 24);
                    for (int dy = 0; dy < 2; dy++) {
                        u32 w = dy ? w1 : w0;
                        u64 W = ((u64)w << 32) | w;
                        for (int p = 0; p < 3; p++) {
                            u64 t = W ^ c1s[p];
                            cnt[2 * p]     = min(cnt[2 * p],     (u32)__popc((u32)t));
                            cnt[2 * p + 1] = min(cnt[2 * p + 1], (u32)__popc((u32)(t >> 32)));
                        }
                    }
                }
                u64 bS[6];
                for (int c = 0; c < 6; c++) bS[c] = __ballot(cnt[c] >= 13);
                if (px == 0) {
                    int sh = lane & 48;
                    u64 rAs = ((bS[0] >> sh) & 0x3FFF) | (((bS[1] >> sh) & 0x3FFF) << 16) | (((bS[2] >> sh) & 0x3FFF) << 32);
                    u64 rBs = ((bS[3] >> sh) & 0x3FFF) | (((bS[4] >> sh) & 0x3FFF) << 16) | (((bS[5] >> sh) & 0x3FFF) << 32);
                    h1As[li][py] = rAs; h1Bs[li][py] = rBs;
                }
            }
        } else {
            u64 c1n[3], c1s[3];
            for (int p = 0; p < 3; p++) { c1n[p] = WL[OC1 + p]; c1s[p] = WL[OC1 + 3 + p]; }
            for (int it = 0; it < 7; it++) {
                int seg = it * 4 + (lane >> 4);
                int im = seg >= 14 ? 1 : 0, py = seg - 14 * im, li = li0 + im;
                int oy = 2 * py;
                u32 rn[6], rs[6];
                for (int k = 0; k < 6; k++) { rn[k] = xn[li][oy + k]; rs[k] = xs[li][oy + k]; }
                int best[6];
                for (int c = 0; c < 6; c++) best[c] = -1000;
                for (int dx = 0; dx < 2; dx++) {
                    int t2 = 2 * pxe + dx;
                    u32 wn0 = 0, ws0 = 0;
                    for (int r = 0; r < 5; r++) {
                        wn0 |= ((rn[r] >> t2) & 31u) << (6 * r);
                        ws0 |= ((rs[r] >> t2) & 31u) << (6 * r);
                    }
                    u32 wn1 = (wn0 >> 6) | (((rn[5] >> t2) & 31u) << 24);
                    u32 ws1 = (ws0 >> 6) | (((rs[5] >> t2) & 31u) << 24);
                    for (int dy = 0; dy < 2; dy++) {
                        u32 wn = dy ? wn1 : wn0, ws = dy ? ws1 : ws0;
                        u64 Wn = ((u64)wn << 32) | wn;
                        u64 Ws = ((u64)ws << 32) | ws;
                        for (int p = 0; p < 3; p++) {
                            u64 m  = Wn & c1n[p];
                            u64 mx = m & (Ws ^ c1s[p]);
                            int a0 = __popc((u32)m) - 2 * __popc((u32)mx);
                            int a1 = __popc((u32)(m >> 32)) - 2 * __popc((u32)(mx >> 32));
                            best[2 * p]     = max(best[2 * p], a0);
                            best[2 * p + 1] = max(best[2 * p + 1], a1);
                        }
                    }
                }
                u64 bS[6], bN[6];
                for (int c = 0; c < 6; c++) {
                    bS[c] = __ballot(best[c] < 0);
                    bN[c] = __ballot(best[c] != 0);
                }
                if (px == 0) {
                    int sh = lane & 48;
                    u64 rAs = ((bS[0] >> sh) & 0x3FFF) | (((bS[1] >> sh) & 0x3FFF) << 16) | (((bS[2] >> sh) & 0x3FFF) << 32);
                    u64 rAn = ((bN[0] >> sh) & 0x3FFF) | (((bN[1] >> sh) & 0x3FFF) << 16) | (((bN[2] >> sh) & 0x3FFF) << 32);
                    u64 rBs = ((bS[3] >> sh) & 0x3FFF) | (((bS[4] >> sh) & 0x3FFF) << 16) | (((bS[5] >> sh) & 0x3FFF) << 32);
                    u64 rBn = ((bN[3] >> sh) & 0x3FFF) | (((bN[4] >> sh) & 0x3FFF) << 16) | (((bN[5] >> sh) & 0x3FFF) << 32);
                    h1As[li][py] = rAs; h1An[li][py] = rAn;
                    h1Bs[li][py] = rBs; h1Bn[li][py] = rBn;
                }
            }
        }
    }
    WB();

    // ---- conv2 + pool: 50 lanes (2 img x 25 points) ----
    if (lane < 14) { int li = li0 + (lane >= 7 ? 1 : 0); int k = lane % 7; h2n[li][k] = 0; h2s[li][k] = 0; }
    if (fastp) {
        if (lane < 50) {
            int im = lane >= 25 ? 1 : 0, p = lane - 25 * im, li = li0 + im;
            int py = p / 5, px2 = p % 5;
            int y0 = 2 * py;
            u32 dsg[2][6];
            for (int r = 0; r < 6; r++) {
                u64 a = h1As[li][y0 + r], b = h1Bs[li][y0 + r];
                for (int dx = 0; dx < 2; dx++) {
                    int t2 = 2 * px2 + dx;
                    u64 as = a >> t2, bs = b >> t2;
                    dsg[dx][r] = (((u32)as & 31u) | ((u32)(as >> 11) & 0x3E0u) | ((u32)(as >> 22) & 0x7C00u))
                               | ((((u32)bs & 31u) | ((u32)(bs >> 11) & 0x3E0u) | ((u32)(bs >> 22) & 0x7C00u)) << 15);
                }
            }
            u64 Ps[2][4];
            for (int dx = 0; dx < 2; dx++)
                for (int r = 0; r < 4; r++)
                    Ps[dx][r] = (u64)dsg[dx][r] | ((u64)dsg[dx][r + 1] << 32);
            u64 sb = 0, nb = 0;
            for (int ch = 0; ch < 16; ch++) {
                u64 w0s = WL[OC2 + ch * 6 + 3], w1s = WL[OC2 + ch * 6 + 4];
                u32 w2s = (u32)WL[OC2 + ch * 6 + 5];
                u32 mn = 255;
                for (int dy = 0; dy < 2; dy++)
                    for (int dx = 0; dx < 2; dx++) {
                        u64 t0 = Ps[dx][dy] ^ w0s, t1 = Ps[dx][dy + 2] ^ w1s;
                        u32 t2v = (dy ? dsg[dx][5] : dsg[dx][4]) ^ w2s;
                        u32 c = __popcll(t0) + __popcll(t1) + __popc(t2v);
                        mn = min(mn, c);
                    }
                sb |= (u64)(mn >= 76 ? 1 : 0) << ch;
                nb |= (u64)(mn != 75 ? 1 : 0) << ch;
            }
            int k = p >> 2, f = p & 3;
            atomicOr(&h2s[li][k], sb << (16 * f));
            atomicOr(&h2n[li][k], nb << (16 * f));
        }
    } else {
        if (lane < 50) {
            int im = lane >= 25 ? 1 : 0, p = lane - 25 * im, li = li0 + im;
            int py = p / 5, px2 = p % 5;
            int y0 = 2 * py;
            u32 dn[2][6], dsg[2][6];
            for (int r = 0; r < 6; r++) {
                u64 a_n = h1An[li][y0 + r], a_s = h1As[li][y0 + r];
                u64 b_n = h1Bn[li][y0 + r], b_s = h1Bs[li][y0 + r];
                for (int dx = 0; dx < 2; dx++) {
                    int t2 = 2 * px2 + dx;
                    u64 an = a_n >> t2, as = a_s >> t2, bn = b_n >> t2, bs = b_s >> t2;
                    dn[dx][r]  = (((u32)an & 31u) | ((u32)(an >> 11) & 0x3E0u) | ((u32)(an >> 22) & 0x7C00u))
                               | ((((u32)bn & 31u) | ((u32)(bn >> 11) & 0x3E0u) | ((u32)(bn >> 22) & 0x7C00u)) << 15);
                    dsg[dx][r] = (((u32)as & 31u) | ((u32)(as >> 11) & 0x3E0u) | ((u32)(as >> 22) & 0x7C00u))
                               | ((((u32)bs & 31u) | ((u32)(bs >> 11) & 0x3E0u) | ((u32)(bs >> 22) & 0x7C00u)) << 15);
                }
            }
            u64 Pn[2][4], Ps[2][4];
            for (int dx = 0; dx < 2; dx++)
                for (int r = 0; r < 4; r++) {
                    Pn[dx][r] = (u64)dn[dx][r]  | ((u64)dn[dx][r + 1]  << 32);
                    Ps[dx][r] = (u64)dsg[dx][r] | ((u64)dsg[dx][r + 1] << 32);
                }
            u64 sb = 0, nb = 0;
            for (int ch = 0; ch < 16; ch++) {
                const u64* wp = &WL[OC2 + ch * 6];
                u64 w0n = wp[0], w1n = wp[1]; u32 w2n = (u32)wp[2];
                u64 w0s = wp[3], w1s = wp[4]; u32 w2s = (u32)wp[5];
                int am = -1000000;
                for (int dy = 0; dy < 2; dy++)
                    for (int dx = 0; dx < 2; dx++) {
                        u64 m0 = Pn[dx][dy] & w0n, m1 = Pn[dx][dy + 2] & w1n;
                        u32 m2 = (dy ? dn[dx][5] : dn[dx][4]) & w2n;
                        u64 x0 = m0 & (Ps[dx][dy] ^ w0s), x1 = m1 & (Ps[dx][dy + 2] ^ w1s);
                        u32 x2 = m2 & ((dy ? dsg[dx][5] : dsg[dx][4]) ^ w2s);
                        int v = __popcll(m0) + __popcll(m1) + __popc(m2)
                              - 2 * (__popcll(x0) + __popcll(x1) + __popc(x2));
                        am = max(am, v);
                    }
                sb |= (u64)sgnb(am) << ch;
                nb |= (u64)nzb(am) << ch;
            }
            int k = p >> 2, f = p & 3;
            atomicOr(&h2s[li][k], sb << (16 * f));
            atomicOr(&h2n[li][k], nb << (16 * f));
        }
    }
    WB();

    // ---- fc1: 400 -> 120 (pad 128); 4 passes; interleaved weights (dwordx4 pairs) ----
    for (int it = 0; it < 4; it++) {
        int im = it >> 1, word = it & 1, li = li0 + im;
        int j = word * 64 + lane;
        const u64* wj = P + OF1 + j * 16;
        int acc = 0;
        for (int k = 0; k < 7; k++) {
            u64 m  = h2n[li][k] & wj[2 * k];
            u64 mx = m & (h2s[li][k] ^ wj[2 * k + 1]);
            acc += __popcll(m) - 2 * __popcll(mx);
        }
        u64 bs = __ballot(acc < 0);
        u64 bn = __ballot(acc != 0);
        if (lane == 0) { f1s[li][word] = bs; f1n[li][word] = bn; }
    }
    WB();

    // ---- fc2: 120 -> 84 (pad 128), interleaved weights ----
    for (int it = 0; it < 4; it++) {
        int im = it >> 1, word = it & 1, li = li0 + im;
        int j = word * 64 + lane;
        const u64* wj = P + OF2 + j * 6;
        u64 m0 = f1n[li][0] & wj[0], m1 = f1n[li][1] & wj[2];
        u64 x0 = m0 & (f1s[li][0] ^ wj[1]), x1 = m1 & (f1s[li][1] ^ wj[3]);
        int acc = __popcll(m0) + __popcll(m1) - 2 * (__popcll(x0) + __popcll(x1));
        u64 bs = __ballot(acc < 0);
        u64 bn = __ballot(acc != 0);
        if (lane == 0) { f2s[li][word] = bs; f2n[li][word] = bn; }
    }
    WB();

    // ---- fc3: 84 -> 10, into LDS staging buffer ----
    if (lane < 32) {
        int im = lane >> 4, j = lane & 15, li = li0 + im;
        if (j < 10) {
            const u64* wj = P + OF3 + j * 4;
            u64 m0 = f2n[li][0] & wj[0], m1 = f2n[li][1] & wj[2];
            u64 x0 = m0 & (f2s[li][0] ^ wj[1]), x1 = m1 & (f2s[li][1] ^ wj[3]);
            int acc = __popcll(m0) + __popcll(m1) - 2 * (__popcll(x0) + __popcll(x1));
            outb[li * 10 + j] = (float)acc;
        }
    }
    __syncthreads();
    // coalesced 320 B block store (full lines -> no RFO write amplification)
    if (tid < G * 10) out[(size_t)img0 * 10 + tid] = outb[tid];
}

extern "C" void kernel_launch(void* const* d_in, const int* in_sizes, int n_in,
                              void* d_out, int out_size, void* d_ws, size_t ws_size,
                              hipStream_t stream) {
    const float* x    = (const float*)d_in[0];
    const float* w1   = (const float*)d_in[1];
    const float* w2   = (const float*)d_in[2];
    const float* wfc1 = (const float*)d_in[3];
    const float* wfc2 = (const float*)d_in[4];
    const float* wfc3 = (const float*)d_in[5];
    float* out = (float*)d_out;
    u64* P = (u64*)d_ws;

    int B = in_sizes[0] / 1024;  // 16384

    pack_w<<<12, 256, 0, stream>>>(w1, w2, wfc1, wfc2, wfc3, P);
    lenet_main<<<B / G, 256, 0, stream>>>(x, P, out);
}

// Round 9
// 148.249 us; speedup vs baseline: 1.1114x; 1.1114x over previous
//
#include <hip/hip_runtime.h>
#include <hip/hip_bf16.h>

typedef unsigned int u32;
typedef unsigned long long u64;

// ---------------- packed-weight layout in d_ws (u64 indices) ----------------
#define OC1 0      // conv1: 3 nz ch-pair words, then 3 sign ch-pair words
#define OC2 8      // conv2: per out-ch 6 u64: [0..2]=nz rows, [3..5]=sign rows
#define WCONV 104
// fc1: per j (pad 128), stride 16: word 2k=nz_k, 2k+1=sign_k (k=0..6), 14/15 pad
#define OF1 104    // 128*16 = 2048
// fc2: per j (pad 128), stride 6: [nz0,sg0,nz1,sg1,pad,pad]
#define OF2 2152   // 128*6 = 768
// fc3: per j (10), stride 4: [nz0,sg0,nz1,sg1]
#define OF3 2920   // 10*4 = 40
#define WTOT 2960

__global__ void pack_w(const float* __restrict__ w1, const float* __restrict__ w2,
                       const float* __restrict__ f1, const float* __restrict__ f2,
                       const float* __restrict__ f3, u64* __restrict__ P) {
    int g = blockIdx.x * 256 + threadIdx.x;
    if (g < 2048) {                      // fc1: j*16 + w, interleaved nz/sign
        int j = g >> 4, w = g & 15;
        u64 v = 0;
        if (w < 14 && j < 120) {
            int k = w >> 1; bool sp = (w & 1);
            for (int f = 0; f < 4; f++) {
                int p = 4 * k + f;
                if (p < 25)
                    for (int ch = 0; ch < 16; ch++) {
                        float x = f1[j * 400 + ch * 25 + p];
                        bool b = sp ? (x < 0.0f) : (x != 0.0f);
                        if (b) v |= 1ull << (f * 16 + ch);
                    }
            }
        }
        P[OF1 + g] = v;
    } else if (g < 2816) {               // fc2: j*6 + w, [nz0,sg0,nz1,sg1,pad,pad]
        int g2 = g - 2048, j = g2 / 6, w = g2 % 6;
        u64 v = 0;
        if (w < 4 && j < 84) {
            int h = w >> 1; bool sp = (w & 1);
            for (int b = 0; b < 64; b++) {
                int k = h * 64 + b;
                if (k < 120) {
                    float x = f2[j * 120 + k];
                    bool bb = sp ? (x < 0.0f) : (x != 0.0f);
                    if (bb) v |= 1ull << b;
                }
            }
        }
        P[OF2 + g2] = v;
    } else if (g < 2856) {               // fc3: j*4 + w, [nz0,sg0,nz1,sg1]
        int g3 = g - 2816, j = g3 >> 2, w = g3 & 3;
        int h = w >> 1; bool sp = (w & 1);
        u64 v = 0;
        for (int b = 0; b < 64; b++) {
            int k = h * 64 + b;
            if (k < 84) {
                float x = f3[j * 84 + k];
                bool bb = sp ? (x < 0.0f) : (x != 0.0f);
                if (bb) v |= 1ull << b;
            }
        }
        P[OF3 + g3] = v;
    } else if (g < 2952) {               // conv2
        int c = g - 2856, ch = c / 6, w = c % 6;
        bool sp = (w >= 3); int wp = w % 3;
        u64 v = 0;
        for (int half = 0; half < 2; half++) {
            int r = 2 * wp + half;
            if (r < 5) {
                u32 rowv = 0;
                for (int ci = 0; ci < 6; ci++)
                    for (int cc = 0; cc < 5; cc++) {
                        float x = w2[((ch * 6 + ci) * 5 + r) * 5 + cc];
                        bool b = sp ? (x < 0.0f) : (x != 0.0f);
                        int bit = (ci < 3) ? (5 * ci + cc) : (15 + 5 * (ci - 3) + cc);
                        if (b) rowv |= 1u << bit;
                    }
                v |= (u64)rowv << (32 * half);
            }
        }
        P[OC2 + ch * 6 + (sp ? 3 : 0) + wp] = v;
    } else if (g < 2958) {               // conv1
        int c = g - 2952;
        int pair = c % 3; bool sp = (c >= 3);
        u64 v = 0;
        for (int half = 0; half < 2; half++) {
            int ch = 2 * pair + half;
            u32 wd = 0;
            for (int r = 0; r < 5; r++)
                for (int cc = 0; cc < 5; cc++) {
                    float x = w1[ch * 25 + r * 5 + cc];
                    bool b = sp ? (x < 0.0f) : (x != 0.0f);
                    if (b) wd |= 1u << (6 * r + cc);
                }
            v |= (u64)wd << (32 * half);
        }
        P[OC1 + (sp ? 3 : 0) + pair] = v;
    }
}

#define G 8  // images per block

__device__ __forceinline__ u32 sgnb(int v) { return (u32)v >> 31; }
__device__ __forceinline__ u32 nzb(int v)  { return (u32)(v | -v) >> 31; }

__global__ __launch_bounds__(256, 8) void lenet_main(const float* __restrict__ X,
                                                     const u64* __restrict__ P,
                                                     float* __restrict__ out) {
    __shared__ u64 WL[WCONV];
    __shared__ u32 xs[G][32], xn[G][32];
    __shared__ u64 h1An[G][14], h1As[G][14], h1Bn[G][14], h1Bs[G][14];
    __shared__ u64 h2n[G][7], h2s[G][7];
    __shared__ u64 f1s[G][2], f1n[G][2], f2s[G][2], f2n[G][2];
    __shared__ u32 anyz, dirty;

    const int tid = threadIdx.x;
    const int img0 = blockIdx.x * G;

    if (tid < WCONV) WL[tid] = P[tid];
    if (tid < G * 7) { int im = tid / 7, k = tid % 7; h2n[im][k] = 0; h2s[im][k] = 0; }
    if (tid == 0) { anyz = 0; dirty = 0; }
    __syncthreads();

    // weight-cleanliness check: every conv nz-plane word must be full (no exact-0 weights)
    if (tid < 51) {
        u64 w, exp;
        if (tid < 48) {
            int ch = tid / 3, k = tid % 3;
            w = WL[OC2 + ch * 6 + k];
            exp = (k < 2) ? 0x3FFFFFFF3FFFFFFFull : 0x000000003FFFFFFFull;
        } else {
            w = WL[OC1 + (tid - 48)];
            exp = 0x1F7DF7DF1F7DF7DFull;
        }
        if (w != exp) dirty = 1;
    }

    // ---- input: float4 load + nibble binarize + shfl-xor OR-reduce; zero detect ----
    {
        const float4* X4 = (const float4*)(X + (size_t)img0 * 1024);
        for (int it = 0; it < G; it++) {
            float4 v = X4[it * 256 + tid];
            u32 s = (v.x < 0.0f ? 1u : 0u) | (v.y < 0.0f ? 2u : 0u)
                  | (v.z < 0.0f ? 4u : 0u) | (v.w < 0.0f ? 8u : 0u);
            u32 n = (v.x != 0.0f ? 1u : 0u) | (v.y != 0.0f ? 2u : 0u)
                  | (v.z != 0.0f ? 4u : 0u) | (v.w != 0.0f ? 8u : 0u);
            if (n != 15u) anyz = 1;               // some component exactly 0.0
            int pos = 4 * (tid & 7);
            u32 sw = s << pos, nw = n << pos;
            sw |= __shfl_xor((int)sw, 1); sw |= __shfl_xor((int)sw, 2); sw |= __shfl_xor((int)sw, 4);
            nw |= __shfl_xor((int)nw, 1); nw |= __shfl_xor((int)nw, 2); nw |= __shfl_xor((int)nw, 4);
            if ((tid & 7) == 0) { xs[it][tid >> 3] = sw; xn[it][tid >> 3] = nw; }
        }
    }
    __syncthreads();

    const bool fastp = ((anyz | dirty) == 0);

    // ---- conv1 + pool: 16-lane segment per (img,row); lane = px; ballot pack ----
    {
        const int px = tid & 15;
        const int pxe = px < 14 ? px : 13;
        if (fastp) {
            // pure XNOR: val = 25 - 2*popc(S^Ws); max-pool == min popc; h1 never 0
            u64 c1s[3];
            for (int p = 0; p < 3; p++) c1s[p] = WL[OC1 + 3 + p];
            for (int it = 0; it < 7; it++) {
                int seg = it * 16 + (tid >> 4);
                int img = seg / 14, py = seg % 14;
                int oy = 2 * py;
                u32 rs[6];
                for (int k = 0; k < 6; k++) rs[k] = xs[img][oy + k];
                u32 cnt[6];
                for (int c = 0; c < 6; c++) cnt[c] = 255;
                for (int dx = 0; dx < 2; dx++) {
                    int t2 = 2 * pxe + dx;
                    u32 w0 = 0;
                    for (int r = 0; r < 5; r++) w0 |= ((rs[r] >> t2) & 31u) << (6 * r);
                    u32 w1 = (w0 >> 6) | (((rs[5] >> t2) & 31u) << 24);
                    for (int dy = 0; dy < 2; dy++) {
                        u32 w = dy ? w1 : w0;
                        u64 W = ((u64)w << 32) | w;
                        for (int p = 0; p < 3; p++) {
                            u64 t = W ^ c1s[p];
                            cnt[2 * p]     = min(cnt[2 * p],     (u32)__popc((u32)t));
                            cnt[2 * p + 1] = min(cnt[2 * p + 1], (u32)__popc((u32)(t >> 32)));
                        }
                    }
                }
                u64 bS[6];
                for (int c = 0; c < 6; c++) bS[c] = __ballot(cnt[c] >= 13);
                if (px == 0) {
                    int sh = tid & 48;
                    u64 rAs = ((bS[0] >> sh) & 0x3FFF) | (((bS[1] >> sh) & 0x3FFF) << 16) | (((bS[2] >> sh) & 0x3FFF) << 32);
                    u64 rBs = ((bS[3] >> sh) & 0x3FFF) | (((bS[4] >> sh) & 0x3FFF) << 16) | (((bS[5] >> sh) & 0x3FFF) << 32);
                    h1As[img][py] = rAs; h1Bs[img][py] = rBs;
                }
            }
        } else {
            // exact ternary path
            u64 c1n[3], c1s[3];
            for (int p = 0; p < 3; p++) { c1n[p] = WL[OC1 + p]; c1s[p] = WL[OC1 + 3 + p]; }
            for (int it = 0; it < 7; it++) {
                int seg = it * 16 + (tid >> 4);
                int img = seg / 14, py = seg % 14;
                int oy = 2 * py;
                u32 rn[6], rs[6];
                for (int k = 0; k < 6; k++) { rn[k] = xn[img][oy + k]; rs[k] = xs[img][oy + k]; }
                int best[6];
                for (int c = 0; c < 6; c++) best[c] = -1000;
                for (int dx = 0; dx < 2; dx++) {
                    int t2 = 2 * pxe + dx;
                    u32 wn0 = 0, ws0 = 0;
                    for (int r = 0; r < 5; r++) {
                        wn0 |= ((rn[r] >> t2) & 31u) << (6 * r);
                        ws0 |= ((rs[r] >> t2) & 31u) << (6 * r);
                    }
                    u32 wn1 = (wn0 >> 6) | (((rn[5] >> t2) & 31u) << 24);
                    u32 ws1 = (ws0 >> 6) | (((rs[5] >> t2) & 31u) << 24);
                    for (int dy = 0; dy < 2; dy++) {
                        u32 wn = dy ? wn1 : wn0, ws = dy ? ws1 : ws0;
                        u64 Wn = ((u64)wn << 32) | wn;
                        u64 Ws = ((u64)ws << 32) | ws;
                        for (int p = 0; p < 3; p++) {
                            u64 m  = Wn & c1n[p];
                            u64 mx = m & (Ws ^ c1s[p]);
                            int a0 = __popc((u32)m) - 2 * __popc((u32)mx);
                            int a1 = __popc((u32)(m >> 32)) - 2 * __popc((u32)(mx >> 32));
                            best[2 * p]     = max(best[2 * p], a0);
                            best[2 * p + 1] = max(best[2 * p + 1], a1);
                        }
                    }
                }
                u64 bS[6], bN[6];
                for (int c = 0; c < 6; c++) {
                    bS[c] = __ballot(best[c] < 0);
                    bN[c] = __ballot(best[c] != 0);
                }
                if (px == 0) {
                    int sh = tid & 48;
                    u64 rAs = ((bS[0] >> sh) & 0x3FFF) | (((bS[1] >> sh) & 0x3FFF) << 16) | (((bS[2] >> sh) & 0x3FFF) << 32);
                    u64 rAn = ((bN[0] >> sh) & 0x3FFF) | (((bN[1] >> sh) & 0x3FFF) << 16) | (((bN[2] >> sh) & 0x3FFF) << 32);
                    u64 rBs = ((bS[3] >> sh) & 0x3FFF) | (((bS[4] >> sh) & 0x3FFF) << 16) | (((bS[5] >> sh) & 0x3FFF) << 32);
                    u64 rBn = ((bN[3] >> sh) & 0x3FFF) | (((bN[4] >> sh) & 0x3FFF) << 16) | (((bN[5] >> sh) & 0x3FFF) << 32);
                    h1As[img][py] = rAs; h1An[img][py] = rAn;
                    h1Bs[img][py] = rBs; h1Bn[img][py] = rBn;
                }
            }
        }
    }
    __syncthreads();

    // ---- conv2 + pool ----
    if (fastp) {
        // h1 in {+-1}: val = 150 - 2*popc(S^Ws); sign: min>=76, nz: min!=75
        for (int idx = tid; idx < G * 25; idx += 256) {
            int img = idx / 25, p = idx % 25, py = p / 5, px = p % 5;
            int y0 = 2 * py;
            u32 dsg[2][6];
            for (int r = 0; r < 6; r++) {
                u64 a = h1As[img][y0 + r], b = h1Bs[img][y0 + r];
                for (int dx = 0; dx < 2; dx++) {
                    int t2 = 2 * px + dx;
                    u64 as = a >> t2, bs = b >> t2;
                    dsg[dx][r] = (((u32)as & 31u) | ((u32)(as >> 11) & 0x3E0u) | ((u32)(as >> 22) & 0x7C00u))
                               | ((((u32)bs & 31u) | ((u32)(bs >> 11) & 0x3E0u) | ((u32)(bs >> 22) & 0x7C00u)) << 15);
                }
            }
            u64 Ps[2][4];
            for (int dx = 0; dx < 2; dx++)
                for (int r = 0; r < 4; r++)
                    Ps[dx][r] = (u64)dsg[dx][r] | ((u64)dsg[dx][r + 1] << 32);
            u64 sb = 0, nb = 0;
            for (int ch = 0; ch < 16; ch++) {
                u64 w0s = WL[OC2 + ch * 6 + 3], w1s = WL[OC2 + ch * 6 + 4];
                u32 w2s = (u32)WL[OC2 + ch * 6 + 5];
                u32 mn = 255;
                for (int dy = 0; dy < 2; dy++)
                    for (int dx = 0; dx < 2; dx++) {
                        u64 t0 = Ps[dx][dy] ^ w0s, t1 = Ps[dx][dy + 2] ^ w1s;
                        u32 t2v = (dy ? dsg[dx][5] : dsg[dx][4]) ^ w2s;
                        u32 c = __popcll(t0) + __popcll(t1) + __popc(t2v);
                        mn = min(mn, c);
                    }
                sb |= (u64)(mn >= 76 ? 1 : 0) << ch;
                nb |= (u64)(mn != 75 ? 1 : 0) << ch;
            }
            int k = p >> 2, f = p & 3;
            atomicOr(&h2s[img][k], sb << (16 * f));
            atomicOr(&h2n[img][k], nb << (16 * f));
        }
    } else {
        for (int idx = tid; idx < G * 25; idx += 256) {
            int img = idx / 25, p = idx % 25, py = p / 5, px = p % 5;
            int y0 = 2 * py;
            u32 dn[2][6], dsg[2][6];
            for (int r = 0; r < 6; r++) {
                u64 a_n = h1An[img][y0 + r], a_s = h1As[img][y0 + r];
                u64 b_n = h1Bn[img][y0 + r], b_s = h1Bs[img][y0 + r];
                for (int dx = 0; dx < 2; dx++) {
                    int t2 = 2 * px + dx;
                    u64 an = a_n >> t2, as = a_s >> t2, bn = b_n >> t2, bs = b_s >> t2;
                    dn[dx][r]  = (((u32)an & 31u) | ((u32)(an >> 11) & 0x3E0u) | ((u32)(an >> 22) & 0x7C00u))
                               | ((((u32)bn & 31u) | ((u32)(bn >> 11) & 0x3E0u) | ((u32)(bn >> 22) & 0x7C00u)) << 15);
                    dsg[dx][r] = (((u32)as & 31u) | ((u32)(as >> 11) & 0x3E0u) | ((u32)(as >> 22) & 0x7C00u))
                               | ((((u32)bs & 31u) | ((u32)(bs >> 11) & 0x3E0u) | ((u32)(bs >> 22) & 0x7C00u)) << 15);
                }
            }
            u64 Pn[2][4], Ps[2][4];
            for (int dx = 0; dx < 2; dx++)
                for (int r = 0; r < 4; r++) {
                    Pn[dx][r] = (u64)dn[dx][r]  | ((u64)dn[dx][r + 1]  << 32);
                    Ps[dx][r] = (u64)dsg[dx][r] | ((u64)dsg[dx][r + 1] << 32);
                }
            u64 sb = 0, nb = 0;
            for (int ch = 0; ch < 16; ch++) {
                const u64* wp = &WL[OC2 + ch * 6];
                u64 w0n = wp[0], w1n = wp[1]; u32 w2n = (u32)wp[2];
                u64 w0s = wp[3], w1s = wp[4]; u32 w2s = (u32)wp[5];
                int am = -1000000;
                for (int dy = 0; dy < 2; dy++)
                    for (int dx = 0; dx < 2; dx++) {
                        u64 m0 = Pn[dx][dy] & w0n, m1 = Pn[dx][dy + 2] & w1n;
                        u32 m2 = (dy ? dn[dx][5] : dn[dx][4]) & w2n;
                        u64 x0 = m0 & (Ps[dx][dy] ^ w0s), x1 = m1 & (Ps[dx][dy + 2] ^ w1s);
                        u32 x2 = m2 & ((dy ? dsg[dx][5] : dsg[dx][4]) ^ w2s);
                        int v = __popcll(m0) + __popcll(m1) + __popc(m2)
                              - 2 * (__popcll(x0) + __popcll(x1) + __popc(x2));
                        am = max(am, v);
                    }
                sb |= (u64)sgnb(am) << ch;
                nb |= (u64)nzb(am) << ch;
            }
            int k = p >> 2, f = p & 3;
            atomicOr(&h2s[img][k], sb << (16 * f));
            atomicOr(&h2n[img][k], nb << (16 * f));
        }
    }
    __syncthreads();

    // ---- fc1: 400 -> 120 (pad 128); interleaved weights (dwordx4 pair merges) ----
    for (int r = 0; r < G / 2; r++) {
        int slot = r * 256 + tid;
        int img = slot >> 7, j = slot & 127, word = (slot >> 6) & 1;
        const u64* wj = P + OF1 + j * 16;
        int acc = 0;
        for (int k = 0; k < 7; k++) {
            u64 m  = h2n[img][k] & wj[2 * k];
            u64 mx = m & (h2s[img][k] ^ wj[2 * k + 1]);
            acc += __popcll(m) - 2 * __popcll(mx);
        }
        u64 bs = __ballot(acc < 0);
        u64 bn = __ballot(acc != 0);
        if ((tid & 63) == 0) { f1s[img][word] = bs; f1n[img][word] = bn; }
    }
    __syncthreads();

    // ---- fc2: 120 -> 84 (pad 128), interleaved weights ----
    for (int r = 0; r < G / 2; r++) {
        int slot = r * 256 + tid;
        int img = slot >> 7, j = slot & 127, word = (slot >> 6) & 1;
        const u64* wj = P + OF2 + j * 6;
        u64 m0 = f1n[img][0] & wj[0], m1 = f1n[img][1] & wj[2];
        u64 x0 = m0 & (f1s[img][0] ^ wj[1]), x1 = m1 & (f1s[img][1] ^ wj[3]);
        int acc = __popcll(m0) + __popcll(m1) - 2 * (__popcll(x0) + __popcll(x1));
        u64 bs = __ballot(acc < 0);
        u64 bn = __ballot(acc != 0);
        if ((tid & 63) == 0) { f2s[img][word] = bs; f2n[img][word] = bn; }
    }
    __syncthreads();

    // ---- fc3: 84 -> 10, fp32 out (block-synchronous coalesced 320 B store) ----
    if (tid < G * 16) {
        int img = tid >> 4, j = tid & 15;
        if (j < 10) {
            const u64* wj = P + OF3 + j * 4;
            u64 m0 = f2n[img][0] & wj[0], m1 = f2n[img][1] & wj[2];
            u64 x0 = m0 & (f2s[img][0] ^ wj[1]), x1 = m1 & (f2s[img][1] ^ wj[3]);
            int acc = __popcll(m0) + __popcll(m1) - 2 * (__popcll(x0) + __popcll(x1));
            out[(size_t)(img0 + img) * 10 + j] = (float)acc;
        }
    }
}

extern "C" void kernel_launch(void* const* d_in, const int* in_sizes, int n_in,
                              void* d_out, int out_size, void* d_ws, size_t ws_size,
                              hipStream_t stream) {
    const float* x    = (const float*)d_in[0];
    const float* w1   = (const float*)d_in[1];
    const float* w2   = (const float*)d_in[2];
    const float* wfc1 = (const float*)d_in[3];
    const float* wfc2 = (const float*)d_in[4];
    const float* wfc3 = (const float*)d_in[5];
    float* out = (float*)d_out;
    u64* P = (u64*)d_ws;

    int B = in_sizes[0] / 1024;  // 16384

    pack_w<<<12, 256, 0, stream>>>(w1, w2, wfc1, wfc2, wfc3, P);
    lenet_main<<<B / G, 256, 0, stream>>>(x, P, out);
}